// Round 5
// baseline (514.080 us; speedup 1.0000x reference)
//
#include <hip/hip_runtime.h>
#include <math.h>

#define BB 512
#define NN 128
#define FF 128
#define KK 4

typedef __attribute__((ext_vector_type(8))) short bf16x8;
typedef __attribute__((ext_vector_type(4))) float f32x4;

__device__ inline unsigned short f2bf(float x) {
  union { float f; unsigned int u; } v; v.f = x;
  unsigned int r = v.u + 0x7fff + ((v.u >> 16) & 1);   // RNE
  return (unsigned short)(r >> 16);
}
__device__ inline float bf2f(unsigned short h) {
  union { unsigned int u; float f; } v; v.u = ((unsigned int)h) << 16; return v.f;
}

// async global->LDS, 16B per lane; lds dest = wave-uniform base + lane*16
__device__ inline void g2l16(const unsigned short* gptr, unsigned short* lptr) {
  __builtin_amdgcn_global_load_lds(
      (const __attribute__((address_space(1))) unsigned int*)gptr,
      (__attribute__((address_space(3))) unsigned int*)lptr, 16, 0, 0);
}

// ---------------------------------------------------------------------------
// E fp32 -> bf16 + degree norm D. One wave per row of 512.
// ---------------------------------------------------------------------------
__global__ __launch_bounds__(256) void k_convE(const float* __restrict__ E,
                                               unsigned short* __restrict__ Eb,
                                               float* __restrict__ Dv) {
  int wave = threadIdx.x >> 6;
  int lane = threadIdx.x & 63;
  int row  = blockIdx.x * 4 + wave;            // [0, BB*NN)
  const float* p = E + (size_t)row * 512 + lane * 8;
  f32x4 a = *(const f32x4*)p;
  f32x4 b = *(const f32x4*)(p + 4);
  float s = a[0] + a[1] + a[2] + a[3] + b[0] + b[1] + b[2] + b[3];
  #pragma unroll
  for (int off = 32; off > 0; off >>= 1) s += __shfl_down(s, off, 64);
  if (lane == 0) Dv[row] = 1.0f / (s + 4.0f);
  union { unsigned short h[8]; f32x4 v; } u;
  u.h[0] = f2bf(a[0]); u.h[1] = f2bf(a[1]); u.h[2] = f2bf(a[2]); u.h[3] = f2bf(a[3]);
  u.h[4] = f2bf(b[0]); u.h[5] = f2bf(b[1]); u.h[6] = f2bf(b[2]); u.h[7] = f2bf(b[3]);
  *(f32x4*)(Eb + (size_t)row * 512 + lane * 8) = u.v;
}

// ---------------------------------------------------------------------------
// H fp32 -> bf16
// ---------------------------------------------------------------------------
__global__ __launch_bounds__(256) void k_convH(const float* __restrict__ H,
                                               unsigned short* __restrict__ Hb) {
  size_t i = ((size_t)blockIdx.x * 256 + threadIdx.x) * 8;
  f32x4 a = *(const f32x4*)(H + i);
  f32x4 b = *(const f32x4*)(H + i + 4);
  union { unsigned short h[8]; f32x4 v; } u;
  u.h[0] = f2bf(a[0]); u.h[1] = f2bf(a[1]); u.h[2] = f2bf(a[2]); u.h[3] = f2bf(a[3]);
  u.h[4] = f2bf(b[0]); u.h[5] = f2bf(b[1]); u.h[6] = f2bf(b[2]); u.h[7] = f2bf(b[3]);
  *(f32x4*)(Hb + i) = u.v;
}

// ---------------------------------------------------------------------------
// W2[c][m]: c<512 -> RW[m*512+c]  (c = n*4+k);  c>=512 -> SW[m*128+(c-512)]
// ---------------------------------------------------------------------------
__global__ __launch_bounds__(256) void k_buildW(const float* __restrict__ RW,
                                                const float* __restrict__ SW,
                                                unsigned short* __restrict__ W2) {
  int idx = blockIdx.x * 256 + threadIdx.x;    // c*128 + m, 81920 total
  int m = idx & 127;
  int c = idx >> 7;
  float v = (c < 512) ? RW[m * 512 + c] : SW[m * 128 + (c - 512)];
  W2[idx] = f2bf(v);
}

// ---------------------------------------------------------------------------
// Fused RGCN layer, one 512-thread block (8 waves) per graph b.
// Per j-strip s (32 j's):
//   - hoist k0=0 phase-1a fragment loads (so they don't FIFO-wait the DMA)
//   - issue 4x global_load_lds per thread: Es <- E[:, s*128..s*128+128)
//     (32 KB bulk in flight; XOR-swizzled colblocks to kill bank conflicts)
//   - phase 1a: Gs[n][jl*4+k] = W2 @ H^T for the strip (direct W2/H loads, L2-hot)
//   - barrier (drains DMA + Gs writes)
//   - phase 2: macc += Es @ Gs^T  -- pure LDS + MFMA
// Then sacc = H @ SW, fused sigmoid epilogue staged through Es for
// coalesced 64B/thread stores.
// LDS: Gs 33 KB + Es 32 KB = 65 KB -> 2 blocks/CU.
// ---------------------------------------------------------------------------
#define GS_PITCH 132

__global__ __launch_bounds__(512, 4) void k_layer(
    const unsigned short* __restrict__ Eb,   // [B][128][512]
    const unsigned short* __restrict__ Hin,  // [B][128][128]
    const unsigned short* __restrict__ W2L,  // [640][128]
    const float* __restrict__ Dv,            // [B][128]
    unsigned short* __restrict__ Hout)       // [B][128][128]
{
  __shared__ unsigned short Gs[128 * GS_PITCH];
  __shared__ unsigned short Es[128 * 128];

  const int b = blockIdx.x;
  const unsigned short* E_b = Eb  + (size_t)b * 65536;
  const unsigned short* H_b = Hin + (size_t)b * 16384;

  const int tid = threadIdx.x;
  const int w = tid >> 6, l = tid & 63;
  const int wr = w >> 1, wc = w & 1;
  const int lq = l >> 4, lm = l & 15;

  f32x4 macc[2][4] = {};

  for (int s = 0; s < 4; ++s) {
    if (s) __syncthreads();   // prev strip's Es/Gs readers done

    // ---- hoisted k0=0 fragment loads for phase 1a ----
    bf16x8 fa0[4], fb0[2];
    #pragma unroll
    for (int f = 0; f < 4; ++f)
      fa0[f] = *(const bf16x8*)(W2L + (w * 64 + f * 16 + lm) * 128 + lq * 8);
    #pragma unroll
    for (int g = 0; g < 2; ++g)
      fb0[g] = *(const bf16x8*)(H_b + (s * 32 + g * 16 + lm) * 128 + lq * 8);

    // ---- issue async Es DMA (swizzled): slot cb holds global cb^(row&15) ----
    #pragma unroll
    for (int r = 0; r < 4; ++r) {
      int R   = r * 32 + w * 4 + (l >> 4);
      int cbg = (l & 15) ^ (R & 15);
      g2l16(E_b + R * 512 + s * 128 + cbg * 8,
            Es + (r * 32 + w * 4) * 128);      // wave-uniform base; +lane*16B in HW
    }

    // ---- phase 1a: Gs = W2 @ H^T for j in [s*32, s*32+32) ----
    f32x4 gacc[4][2] = {};
    #pragma unroll
    for (int f = 0; f < 4; ++f)
      #pragma unroll
      for (int g = 0; g < 2; ++g)
        gacc[f][g] = __builtin_amdgcn_mfma_f32_16x16x32_bf16(fa0[f], fb0[g], gacc[f][g], 0, 0, 0);
    #pragma unroll
    for (int k0 = 32; k0 < 128; k0 += 32) {
      bf16x8 fa[4], fb[2];
      #pragma unroll
      for (int f = 0; f < 4; ++f)
        fa[f] = *(const bf16x8*)(W2L + (w * 64 + f * 16 + lm) * 128 + k0 + lq * 8);
      #pragma unroll
      for (int g = 0; g < 2; ++g)
        fb[g] = *(const bf16x8*)(H_b + (s * 32 + g * 16 + lm) * 128 + k0 + lq * 8);
      #pragma unroll
      for (int f = 0; f < 4; ++f)
        #pragma unroll
        for (int g = 0; g < 2; ++g)
          gacc[f][g] = __builtin_amdgcn_mfma_f32_16x16x32_bf16(fa[f], fb[g], gacc[f][g], 0, 0, 0);
    }
    #pragma unroll
    for (int f = 0; f < 4; ++f) {
      int n = w * 16 + f * 4 + lq;             // c = n*4 + reg(k)
      #pragma unroll
      for (int g = 0; g < 2; ++g) {
        int jl = g * 16 + lm;
        union { unsigned short h4[4]; uint2 v; } u;
        u.h4[0] = f2bf(gacc[f][g][0]); u.h4[1] = f2bf(gacc[f][g][1]);
        u.h4[2] = f2bf(gacc[f][g][2]); u.h4[3] = f2bf(gacc[f][g][3]);
        *(uint2*)(&Gs[n * GS_PITCH + jl * 4]) = u.v;
      }
    }
    __syncthreads();   // drains Gs writes AND the Es DMA (vmcnt(0) at barrier)

    // ---- phase 2: macc += Es @ Gs^T, all LDS ----
    #pragma unroll
    for (int kt = 0; kt < 4; ++kt) {
      bf16x8 ea[2], fb[4];
      #pragma unroll
      for (int f = 0; f < 2; ++f) {
        int i  = wr * 32 + f * 16 + lm;        // i & 15 == lm
        int cb = (kt * 4 + lq) ^ lm;           // un-swizzle
        ea[f] = *(const bf16x8*)(Es + i * 128 + cb * 8);
      }
      #pragma unroll
      for (int g = 0; g < 4; ++g)
        fb[g] = *(const bf16x8*)(&Gs[(wc * 64 + g * 16 + lm) * GS_PITCH + kt * 32 + lq * 8]);
      #pragma unroll
      for (int f = 0; f < 2; ++f)
        #pragma unroll
        for (int g = 0; g < 4; ++g)
          macc[f][g] = __builtin_amdgcn_mfma_f32_16x16x32_bf16(ea[f], fb[g], macc[f][g], 0, 0, 0);
    }
  }

  // ---- phase 1b: sacc = Hin @ SW (cols 512..639 of W2L), same (i,n) map ----
  f32x4 sacc[2][4] = {};
  #pragma unroll
  for (int k0 = 0; k0 < 128; k0 += 32) {
    bf16x8 fa[2], fb[4];
    #pragma unroll
    for (int f = 0; f < 2; ++f)
      fa[f] = *(const bf16x8*)(H_b + (wr * 32 + f * 16 + lm) * 128 + k0 + lq * 8);
    #pragma unroll
    for (int g = 0; g < 4; ++g)
      fb[g] = *(const bf16x8*)(W2L + (512 + wc * 64 + g * 16 + lm) * 128 + k0 + lq * 8);
    #pragma unroll
    for (int f = 0; f < 2; ++f)
      #pragma unroll
      for (int g = 0; g < 4; ++g)
        sacc[f][g] = __builtin_amdgcn_mfma_f32_16x16x32_bf16(fa[f], fb[g], sacc[f][g], 0, 0, 0);
  }

  // ---- epilogue: fuse, stage rows in Es, coalesced 64B/thread stores ----
  const float* dvb = Dv + b * 128;
  __syncthreads();   // all phase-2 Es readers done before overwrite
  #pragma unroll
  for (int f = 0; f < 2; ++f) {
    int i0 = wr * 32 + f * 16 + lq * 4;
    f32x4 d = *(const f32x4*)(dvb + i0);
    #pragma unroll
    for (int g = 0; g < 4; ++g) {
      int n = wc * 64 + g * 16 + lm;
      #pragma unroll
      for (int r = 0; r < 4; ++r) {
        float v = fmaf(macc[f][g][r], d[r], sacc[f][g][r]);
        Es[(i0 + r) * 128 + n] = f2bf(1.0f / (1.0f + __expf(-v)));
      }
    }
  }
  __syncthreads();
  unsigned short* O_b = Hout + (size_t)b * 16384;
  {
    int off = tid * 32;                        // 32 ushorts = 64 B per thread
    f32x4 v0 = *(const f32x4*)(Es + off);
    f32x4 v1 = *(const f32x4*)(Es + off + 8);
    f32x4 v2 = *(const f32x4*)(Es + off + 16);
    f32x4 v3 = *(const f32x4*)(Es + off + 24);
    *(f32x4*)(O_b + off)      = v0;
    *(f32x4*)(O_b + off + 8)  = v1;
    *(f32x4*)(O_b + off + 16) = v2;
    *(f32x4*)(O_b + off + 24) = v3;
  }
}

// ---------------------------------------------------------------------------
// MLP head on bf16 H
// ---------------------------------------------------------------------------
__global__ __launch_bounds__(256) void k_mlp(
    const unsigned short* __restrict__ H,   // [B*N][128] bf16
    const float* __restrict__ W1,  // [128][20]
    const float* __restrict__ b1,  // [20]
    const float* __restrict__ W2,  // [20]
    const float* __restrict__ b2,  // [1]
    float* __restrict__ sumOut)
{
  __shared__ float W1s[128 * 20];
  __shared__ float b1s[20], W2s[20];
  __shared__ float red[256];
  for (int i = threadIdx.x; i < 2560; i += 256) W1s[i] = W1[i];
  if (threadIdx.x < 20) { b1s[threadIdx.x] = b1[threadIdx.x]; W2s[threadIdx.x] = W2[threadIdx.x]; }
  __syncthreads();

  int row = blockIdx.x * 256 + threadIdx.x;
  float h[20];
  #pragma unroll
  for (int j = 0; j < 20; ++j) h[j] = b1s[j];
  const unsigned short* hr = H + (size_t)row * 128;
  for (int m8 = 0; m8 < 128; m8 += 8) {
    f32x4 pk = *(const f32x4*)(hr + m8);
    const unsigned short* us = (const unsigned short*)&pk;
    #pragma unroll
    for (int e = 0; e < 8; ++e) {
      float x = bf2f(us[e]);
      #pragma unroll
      for (int j = 0; j < 20; ++j) h[j] = fmaf(x, W1s[(m8 + e) * 20 + j], h[j]);
    }
  }
  float v = b2[0];
  #pragma unroll
  for (int j = 0; j < 20; ++j) {
    float t = h[j];
    t = fmaxf(t, 0.1f * t);
    v = fmaf(t, W2s[j], v);
  }
  float s = 1.0f / (1.0f + __expf(-v));

  red[threadIdx.x] = s;
  __syncthreads();
  #pragma unroll
  for (int off = 128; off > 0; off >>= 1) {
    if (threadIdx.x < off) red[threadIdx.x] += red[threadIdx.x + off];
    __syncthreads();
  }
  if (threadIdx.x == 0) atomicAdd(sumOut, red[0]);
}

__global__ void k_final(const float* __restrict__ sum, float* __restrict__ out) {
  out[0] = sum[0] * (1.0f / 65536.0f);
}

// ---------------------------------------------------------------------------
extern "C" void kernel_launch(void* const* d_in, const int* in_sizes, int n_in,
                              void* d_out, int out_size, void* d_ws, size_t ws_size,
                              hipStream_t stream) {
  const float* H   = (const float*)d_in[0];
  const float* E   = (const float*)d_in[1];
  const float* RW1 = (const float*)d_in[2];
  const float* SW1 = (const float*)d_in[3];
  const float* RW2 = (const float*)d_in[4];
  const float* SW2 = (const float*)d_in[5];
  const float* RW3 = (const float*)d_in[6];
  const float* SW3 = (const float*)d_in[7];
  const float* W1  = (const float*)d_in[8];
  const float* b1  = (const float*)d_in[9];
  const float* W2  = (const float*)d_in[10];
  const float* b2  = (const float*)d_in[11];
  float* out = (float*)d_out;

  char* w = (char*)d_ws;
  float*          wsD   = (float*)w;           w += (size_t)65536 * 4;
  unsigned short* wsEb  = (unsigned short*)w;  w += (size_t)33554432 * 2;
  unsigned short* wsHa  = (unsigned short*)w;  w += (size_t)8388608 * 2;
  unsigned short* wsHb  = (unsigned short*)w;  w += (size_t)8388608 * 2;
  unsigned short* wsW2  = (unsigned short*)w;  w += (size_t)3 * 81920 * 2;
  float*          wsSum = (float*)w;           w += 256;

  k_convE<<<BB * NN / 4, 256, 0, stream>>>(E, wsEb, wsD);
  k_convH<<<8388608 / (256 * 8), 256, 0, stream>>>(H, wsHa);
  k_buildW<<<320, 256, 0, stream>>>(RW1, SW1, wsW2);
  k_buildW<<<320, 256, 0, stream>>>(RW2, SW2, wsW2 + 81920);
  k_buildW<<<320, 256, 0, stream>>>(RW3, SW3, wsW2 + 163840);
  hipMemsetAsync(wsSum, 0, sizeof(float), stream);

  // fused layers (one 512-thread block per graph)
  k_layer<<<BB, 512, 0, stream>>>(wsEb, wsHa, wsW2,          wsD, wsHb);
  k_layer<<<BB, 512, 0, stream>>>(wsEb, wsHb, wsW2 + 81920,  wsD, wsHa);
  k_layer<<<BB, 512, 0, stream>>>(wsEb, wsHa, wsW2 + 163840, wsD, wsHb);

  k_mlp<<<BB * NN / 256, 256, 0, stream>>>(wsHb, W1, b1, W2, b2, wsSum);
  k_final<<<1, 1, 0, stream>>>(wsSum, out);
}

// Round 6
// 434.685 us; speedup vs baseline: 1.1826x; 1.1826x over previous
//
#include <hip/hip_runtime.h>
#include <math.h>

#define BB 512
#define NN 128
#define FF 128
#define KK 4

typedef __attribute__((ext_vector_type(8))) short bf16x8;
typedef __attribute__((ext_vector_type(4))) float f32x4;

__device__ inline unsigned short f2bf(float x) {
  union { float f; unsigned int u; } v; v.f = x;
  unsigned int r = v.u + 0x7fff + ((v.u >> 16) & 1);   // RNE
  return (unsigned short)(r >> 16);
}
__device__ inline float bf2f(unsigned short h) {
  union { unsigned int u; float f; } v; v.u = ((unsigned int)h) << 16; return v.f;
}

// async global->LDS, 16B per lane; lds dest = wave-uniform base + lane*16
__device__ inline void g2l16(const unsigned short* gptr, unsigned short* lptr) {
  __builtin_amdgcn_global_load_lds(
      (const __attribute__((address_space(1))) unsigned int*)gptr,
      (__attribute__((address_space(3))) unsigned int*)lptr, 16, 0, 0);
}

// ---------------------------------------------------------------------------
// E fp32 -> bf16 + degree norm D. One wave per row of 512.
// ---------------------------------------------------------------------------
__global__ __launch_bounds__(256) void k_convE(const float* __restrict__ E,
                                               unsigned short* __restrict__ Eb,
                                               float* __restrict__ Dv) {
  int wave = threadIdx.x >> 6;
  int lane = threadIdx.x & 63;
  int row  = blockIdx.x * 4 + wave;            // [0, BB*NN)
  const float* p = E + (size_t)row * 512 + lane * 8;
  f32x4 a = *(const f32x4*)p;
  f32x4 b = *(const f32x4*)(p + 4);
  float s = a[0] + a[1] + a[2] + a[3] + b[0] + b[1] + b[2] + b[3];
  #pragma unroll
  for (int off = 32; off > 0; off >>= 1) s += __shfl_down(s, off, 64);
  if (lane == 0) Dv[row] = 1.0f / (s + 4.0f);
  union { unsigned short h[8]; f32x4 v; } u;
  u.h[0] = f2bf(a[0]); u.h[1] = f2bf(a[1]); u.h[2] = f2bf(a[2]); u.h[3] = f2bf(a[3]);
  u.h[4] = f2bf(b[0]); u.h[5] = f2bf(b[1]); u.h[6] = f2bf(b[2]); u.h[7] = f2bf(b[3]);
  *(f32x4*)(Eb + (size_t)row * 512 + lane * 8) = u.v;
}

// ---------------------------------------------------------------------------
// H fp32 -> bf16
// ---------------------------------------------------------------------------
__global__ __launch_bounds__(256) void k_convH(const float* __restrict__ H,
                                               unsigned short* __restrict__ Hb) {
  size_t i = ((size_t)blockIdx.x * 256 + threadIdx.x) * 8;
  f32x4 a = *(const f32x4*)(H + i);
  f32x4 b = *(const f32x4*)(H + i + 4);
  union { unsigned short h[8]; f32x4 v; } u;
  u.h[0] = f2bf(a[0]); u.h[1] = f2bf(a[1]); u.h[2] = f2bf(a[2]); u.h[3] = f2bf(a[3]);
  u.h[4] = f2bf(b[0]); u.h[5] = f2bf(b[1]); u.h[6] = f2bf(b[2]); u.h[7] = f2bf(b[3]);
  *(f32x4*)(Hb + i) = u.v;
}

// ---------------------------------------------------------------------------
// W2[c][m]: c<512 -> RW[m*512+c]  (c = n*4+k);  c>=512 -> SW[m*128+(c-512)]
// ---------------------------------------------------------------------------
__global__ __launch_bounds__(256) void k_buildW(const float* __restrict__ RW,
                                                const float* __restrict__ SW,
                                                unsigned short* __restrict__ W2) {
  int idx = blockIdx.x * 256 + threadIdx.x;    // c*128 + m, 81920 total
  int m = idx & 127;
  int c = idx >> 7;
  float v = (c < 512) ? RW[m * 512 + c] : SW[m * 128 + (c - 512)];
  W2[idx] = f2bf(v);
}

// ---------------------------------------------------------------------------
// Fused RGCN layer, one 512-thread block (8 waves) per graph b.
// Identical structure to round 5; ONLY change: __launch_bounds__(512, 2).
// hipcc's 2nd arg is CUDA-semantics min BLOCKS/CU: (512,4) forced 32 waves/CU
// -> 64-VGPR cap -> ~68 MB/dispatch scratch spill traffic (r5 counters).
// (512,2) -> 128-VGPR cap; kernel needs ~110 live; LDS (65 KB) already
// limits to 2 blocks/CU, so occupancy is unchanged and spills disappear.
// ---------------------------------------------------------------------------
#define GS_PITCH 132

__global__ __launch_bounds__(512, 2) void k_layer(
    const unsigned short* __restrict__ Eb,   // [B][128][512]
    const unsigned short* __restrict__ Hin,  // [B][128][128]
    const unsigned short* __restrict__ W2L,  // [640][128]
    const float* __restrict__ Dv,            // [B][128]
    unsigned short* __restrict__ Hout)       // [B][128][128]
{
  __shared__ unsigned short Gs[128 * GS_PITCH];
  __shared__ unsigned short Es[128 * 128];

  const int b = blockIdx.x;
  const unsigned short* E_b = Eb  + (size_t)b * 65536;
  const unsigned short* H_b = Hin + (size_t)b * 16384;

  const int tid = threadIdx.x;
  const int w = tid >> 6, l = tid & 63;
  const int wr = w >> 1, wc = w & 1;
  const int lq = l >> 4, lm = l & 15;

  f32x4 macc[2][4] = {};

  for (int s = 0; s < 4; ++s) {
    if (s) __syncthreads();   // prev strip's Es/Gs readers done

    // ---- hoisted k0=0 fragment loads for phase 1a ----
    bf16x8 fa0[4], fb0[2];
    #pragma unroll
    for (int f = 0; f < 4; ++f)
      fa0[f] = *(const bf16x8*)(W2L + (w * 64 + f * 16 + lm) * 128 + lq * 8);
    #pragma unroll
    for (int g = 0; g < 2; ++g)
      fb0[g] = *(const bf16x8*)(H_b + (s * 32 + g * 16 + lm) * 128 + lq * 8);

    // ---- issue async Es DMA (swizzled): slot cb holds global cb^(row&15) ----
    #pragma unroll
    for (int r = 0; r < 4; ++r) {
      int R   = r * 32 + w * 4 + (l >> 4);
      int cbg = (l & 15) ^ (R & 15);
      g2l16(E_b + R * 512 + s * 128 + cbg * 8,
            Es + (r * 32 + w * 4) * 128);      // wave-uniform base; +lane*16B in HW
    }

    // ---- phase 1a: Gs = W2 @ H^T for j in [s*32, s*32+32) ----
    f32x4 gacc[4][2] = {};
    #pragma unroll
    for (int f = 0; f < 4; ++f)
      #pragma unroll
      for (int g = 0; g < 2; ++g)
        gacc[f][g] = __builtin_amdgcn_mfma_f32_16x16x32_bf16(fa0[f], fb0[g], gacc[f][g], 0, 0, 0);
    #pragma unroll
    for (int k0 = 32; k0 < 128; k0 += 32) {
      bf16x8 fa[4], fb[2];
      #pragma unroll
      for (int f = 0; f < 4; ++f)
        fa[f] = *(const bf16x8*)(W2L + (w * 64 + f * 16 + lm) * 128 + k0 + lq * 8);
      #pragma unroll
      for (int g = 0; g < 2; ++g)
        fb[g] = *(const bf16x8*)(H_b + (s * 32 + g * 16 + lm) * 128 + k0 + lq * 8);
      #pragma unroll
      for (int f = 0; f < 4; ++f)
        #pragma unroll
        for (int g = 0; g < 2; ++g)
          gacc[f][g] = __builtin_amdgcn_mfma_f32_16x16x32_bf16(fa[f], fb[g], gacc[f][g], 0, 0, 0);
    }
    #pragma unroll
    for (int f = 0; f < 4; ++f) {
      int n = w * 16 + f * 4 + lq;             // c = n*4 + reg(k)
      #pragma unroll
      for (int g = 0; g < 2; ++g) {
        int jl = g * 16 + lm;
        union { unsigned short h4[4]; uint2 v; } u;
        u.h4[0] = f2bf(gacc[f][g][0]); u.h4[1] = f2bf(gacc[f][g][1]);
        u.h4[2] = f2bf(gacc[f][g][2]); u.h4[3] = f2bf(gacc[f][g][3]);
        *(uint2*)(&Gs[n * GS_PITCH + jl * 4]) = u.v;
      }
    }
    __syncthreads();   // drains Gs writes AND the Es DMA (vmcnt(0) at barrier)

    // ---- phase 2: macc += Es @ Gs^T, all LDS ----
    #pragma unroll
    for (int kt = 0; kt < 4; ++kt) {
      bf16x8 ea[2], fb[4];
      #pragma unroll
      for (int f = 0; f < 2; ++f) {
        int i  = wr * 32 + f * 16 + lm;        // i & 15 == lm
        int cb = (kt * 4 + lq) ^ lm;           // un-swizzle
        ea[f] = *(const bf16x8*)(Es + i * 128 + cb * 8);
      }
      #pragma unroll
      for (int g = 0; g < 4; ++g)
        fb[g] = *(const bf16x8*)(&Gs[(wc * 64 + g * 16 + lm) * GS_PITCH + kt * 32 + lq * 8]);
      #pragma unroll
      for (int f = 0; f < 2; ++f)
        #pragma unroll
        for (int g = 0; g < 4; ++g)
          macc[f][g] = __builtin_amdgcn_mfma_f32_16x16x32_bf16(ea[f], fb[g], macc[f][g], 0, 0, 0);
    }
  }

  // ---- phase 1b: sacc = Hin @ SW (cols 512..639 of W2L), same (i,n) map ----
  f32x4 sacc[2][4] = {};
  #pragma unroll
  for (int k0 = 0; k0 < 128; k0 += 32) {
    bf16x8 fa[2], fb[4];
    #pragma unroll
    for (int f = 0; f < 2; ++f)
      fa[f] = *(const bf16x8*)(H_b + (wr * 32 + f * 16 + lm) * 128 + k0 + lq * 8);
    #pragma unroll
    for (int g = 0; g < 4; ++g)
      fb[g] = *(const bf16x8*)(W2L + (512 + wc * 64 + g * 16 + lm) * 128 + k0 + lq * 8);
    #pragma unroll
    for (int f = 0; f < 2; ++f)
      #pragma unroll
      for (int g = 0; g < 4; ++g)
        sacc[f][g] = __builtin_amdgcn_mfma_f32_16x16x32_bf16(fa[f], fb[g], sacc[f][g], 0, 0, 0);
  }

  // ---- epilogue: fuse, stage rows in Es, coalesced 64B/thread stores ----
  const float* dvb = Dv + b * 128;
  __syncthreads();   // all phase-2 Es readers done before overwrite
  #pragma unroll
  for (int f = 0; f < 2; ++f) {
    int i0 = wr * 32 + f * 16 + lq * 4;
    f32x4 d = *(const f32x4*)(dvb + i0);
    #pragma unroll
    for (int g = 0; g < 4; ++g) {
      int n = wc * 64 + g * 16 + lm;
      #pragma unroll
      for (int r = 0; r < 4; ++r) {
        float v = fmaf(macc[f][g][r], d[r], sacc[f][g][r]);
        Es[(i0 + r) * 128 + n] = f2bf(1.0f / (1.0f + __expf(-v)));
      }
    }
  }
  __syncthreads();
  unsigned short* O_b = Hout + (size_t)b * 16384;
  {
    int off = tid * 32;                        // 32 ushorts = 64 B per thread
    f32x4 v0 = *(const f32x4*)(Es + off);
    f32x4 v1 = *(const f32x4*)(Es + off + 8);
    f32x4 v2 = *(const f32x4*)(Es + off + 16);
    f32x4 v3 = *(const f32x4*)(Es + off + 24);
    *(f32x4*)(O_b + off)      = v0;
    *(f32x4*)(O_b + off + 8)  = v1;
    *(f32x4*)(O_b + off + 16) = v2;
    *(f32x4*)(O_b + off + 24) = v3;
  }
}

// ---------------------------------------------------------------------------
// MLP head on bf16 H
// ---------------------------------------------------------------------------
__global__ __launch_bounds__(256) void k_mlp(
    const unsigned short* __restrict__ H,   // [B*N][128] bf16
    const float* __restrict__ W1,  // [128][20]
    const float* __restrict__ b1,  // [20]
    const float* __restrict__ W2,  // [20]
    const float* __restrict__ b2,  // [1]
    float* __restrict__ sumOut)
{
  __shared__ float W1s[128 * 20];
  __shared__ float b1s[20], W2s[20];
  __shared__ float red[256];
  for (int i = threadIdx.x; i < 2560; i += 256) W1s[i] = W1[i];
  if (threadIdx.x < 20) { b1s[threadIdx.x] = b1[threadIdx.x]; W2s[threadIdx.x] = W2[threadIdx.x]; }
  __syncthreads();

  int row = blockIdx.x * 256 + threadIdx.x;
  float h[20];
  #pragma unroll
  for (int j = 0; j < 20; ++j) h[j] = b1s[j];
  const unsigned short* hr = H + (size_t)row * 128;
  for (int m8 = 0; m8 < 128; m8 += 8) {
    f32x4 pk = *(const f32x4*)(hr + m8);
    const unsigned short* us = (const unsigned short*)&pk;
    #pragma unroll
    for (int e = 0; e < 8; ++e) {
      float x = bf2f(us[e]);
      #pragma unroll
      for (int j = 0; j < 20; ++j) h[j] = fmaf(x, W1s[(m8 + e) * 20 + j], h[j]);
    }
  }
  float v = b2[0];
  #pragma unroll
  for (int j = 0; j < 20; ++j) {
    float t = h[j];
    t = fmaxf(t, 0.1f * t);
    v = fmaf(t, W2s[j], v);
  }
  float s = 1.0f / (1.0f + __expf(-v));

  red[threadIdx.x] = s;
  __syncthreads();
  #pragma unroll
  for (int off = 128; off > 0; off >>= 1) {
    if (threadIdx.x < off) red[threadIdx.x] += red[threadIdx.x + off];
    __syncthreads();
  }
  if (threadIdx.x == 0) atomicAdd(sumOut, red[0]);
}

__global__ void k_final(const float* __restrict__ sum, float* __restrict__ out) {
  out[0] = sum[0] * (1.0f / 65536.0f);
}

// ---------------------------------------------------------------------------
extern "C" void kernel_launch(void* const* d_in, const int* in_sizes, int n_in,
                              void* d_out, int out_size, void* d_ws, size_t ws_size,
                              hipStream_t stream) {
  const float* H   = (const float*)d_in[0];
  const float* E   = (const float*)d_in[1];
  const float* RW1 = (const float*)d_in[2];
  const float* SW1 = (const float*)d_in[3];
  const float* RW2 = (const float*)d_in[4];
  const float* SW2 = (const float*)d_in[5];
  const float* RW3 = (const float*)d_in[6];
  const float* SW3 = (const float*)d_in[7];
  const float* W1  = (const float*)d_in[8];
  const float* b1  = (const float*)d_in[9];
  const float* W2  = (const float*)d_in[10];
  const float* b2  = (const float*)d_in[11];
  float* out = (float*)d_out;

  char* w = (char*)d_ws;
  float*          wsD   = (float*)w;           w += (size_t)65536 * 4;
  unsigned short* wsEb  = (unsigned short*)w;  w += (size_t)33554432 * 2;
  unsigned short* wsHa  = (unsigned short*)w;  w += (size_t)8388608 * 2;
  unsigned short* wsHb  = (unsigned short*)w;  w += (size_t)8388608 * 2;
  unsigned short* wsW2  = (unsigned short*)w;  w += (size_t)3 * 81920 * 2;
  float*          wsSum = (float*)w;           w += 256;

  k_convE<<<BB * NN / 4, 256, 0, stream>>>(E, wsEb, wsD);
  k_convH<<<8388608 / (256 * 8), 256, 0, stream>>>(H, wsHa);
  k_buildW<<<320, 256, 0, stream>>>(RW1, SW1, wsW2);
  k_buildW<<<320, 256, 0, stream>>>(RW2, SW2, wsW2 + 81920);
  k_buildW<<<320, 256, 0, stream>>>(RW3, SW3, wsW2 + 163840);
  hipMemsetAsync(wsSum, 0, sizeof(float), stream);

  // fused layers (one 512-thread block per graph)
  k_layer<<<BB, 512, 0, stream>>>(wsEb, wsHa, wsW2,          wsD, wsHb);
  k_layer<<<BB, 512, 0, stream>>>(wsEb, wsHb, wsW2 + 81920,  wsD, wsHa);
  k_layer<<<BB, 512, 0, stream>>>(wsEb, wsHa, wsW2 + 163840, wsD, wsHb);

  k_mlp<<<BB * NN / 256, 256, 0, stream>>>(wsHb, W1, b1, W2, b2, wsSum);
  k_final<<<1, 1, 0, stream>>>(wsSum, out);
}